// Round 4
// baseline (1027.096 us; speedup 1.0000x reference)
//
#include <hip/hip_runtime.h>

// GCN 2-layer: out = S·relu(S·(x·W1)+b1)·W2 + b2, S = D^-1/2 (A+I) D^-1/2
// R3: exact counting-sort of edges into 256-node dst-buckets (hist/scan/fill,
// deterministic offsets, zero global scatter), per-bucket LDS-accumulate
// aggregation. Layer-2 epilogue fuses the 16x64 W2 matmul. No overflow paths,
// no global memset needed.

constexpr int BKT_BITS = 8;
constexpr int BKT = 1 << BKT_BITS;   // nodes per bucket
constexpr int EPB = 16384;           // edges per binning block

// ---- pass 1: per-block bucket histogram -----------------------------------
__global__ __launch_bounds__(256) void k_hist(
    const int* __restrict__ dst, int* __restrict__ hist, int ne, int nb) {
  extern __shared__ int sh[];
  for (int i = threadIdx.x; i < nb; i += 256) sh[i] = 0;
  __syncthreads();
  int base = blockIdx.x * EPB;
  int end = min(base + EPB, ne);
  for (int e = base + threadIdx.x; e < end; e += 256)
    atomicAdd(&sh[dst[e] >> BKT_BITS], 1);
  __syncthreads();
  for (int i = threadIdx.x; i < nb; i += 256) hist[blockIdx.x * nb + i] = sh[i];
}

// ---- pass 2: exact offsets: bstart[k], base[b][k] -------------------------
__global__ void k_scan(const int* __restrict__ hist, int* __restrict__ base,
                       int* __restrict__ bstart, int nblk, int nb) {
  for (int k = threadIdx.x; k < nb; k += 256) {
    int s = 0;
    for (int b = 0; b < nblk; ++b) s += hist[b * nb + k];
    bstart[k] = s;
  }
  __syncthreads();
  if (threadIdx.x == 0) {
    int acc = 0;
    for (int k = 0; k < nb; ++k) { int v = bstart[k]; bstart[k] = acc; acc += v; }
    bstart[nb] = acc;
  }
  __syncthreads();
  for (int k = threadIdx.x; k < nb; k += 256) {
    int run = bstart[k];
    for (int b = 0; b < nblk; ++b) { base[b * nb + k] = run; run += hist[b * nb + k]; }
  }
}

// ---- pass 3: scatter records to bucket-contiguous array -------------------
// rec.x = src | (dlocal << 20), rec.y = bits(w)
__global__ __launch_bounds__(256) void k_binfill(
    const int* __restrict__ ei, const float* __restrict__ ew,
    const int* __restrict__ base, uint2* __restrict__ recs, int ne, int nb) {
  extern __shared__ int cur[];
  for (int i = threadIdx.x; i < nb; i += 256) cur[i] = base[blockIdx.x * nb + i];
  __syncthreads();
  int bs = blockIdx.x * EPB;
  int end = min(bs + EPB, ne);
  for (int e = bs + threadIdx.x; e < end; e += 256) {
    int s = ei[e];
    int d = ei[ne + e];
    float w = ew[e];
    int bkt = d >> BKT_BITS;
    int pos = atomicAdd(&cur[bkt], 1);
    recs[pos] = make_uint2((unsigned)s | ((unsigned)(d & (BKT - 1)) << 20),
                           __float_as_uint(w));
  }
}

// ---- degree per bucket -> dinv --------------------------------------------
__global__ __launch_bounds__(256) void k_bdeg(
    const uint2* __restrict__ recs, const int* __restrict__ bstart,
    float* __restrict__ dinv, int n) {
  __shared__ float sdeg[BKT];
  for (int i = threadIdx.x; i < BKT; i += 256) sdeg[i] = 0.f;
  __syncthreads();
  int k = blockIdx.x;
  int s0 = bstart[k], s1 = bstart[k + 1];
  for (int e = s0 + threadIdx.x; e < s1; e += 256) {
    uint2 r = recs[e];
    atomicAdd(&sdeg[(r.x >> 20) & (BKT - 1)], __uint_as_float(r.y));
  }
  __syncthreads();
  int nbase = k << BKT_BITS;
  for (int i = threadIdx.x; i < BKT; i += 256) {
    int node = nbase + i;
    if (node < n) dinv[node] = 1.0f / sqrtf(sdeg[i] + 1.0f);
  }
}

// ---- h1pre = x @ W1  (N x 512 @ 512 x 16), unchanged from R2 --------------
__global__ __launch_bounds__(256) void k_xw1(
    const float* __restrict__ x, const float* __restrict__ W1,
    float* __restrict__ h1pre, int n) {
  __shared__ float W1t[16 * 512];
  {
#pragma unroll
    for (int i = 0; i < 32; ++i) {
      int idx = threadIdx.x + i * 256;     // source flat index = k*16 + j
      int k = idx >> 4, j = idx & 15;
      W1t[j * 512 + k] = W1[idx];
    }
  }
  __syncthreads();
  int gtid = blockIdx.x * 256 + threadIdx.x;
  int rp = gtid >> 2, q = gtid & 3;
  int r0 = rp * 2;
  if (r0 >= n) return;
  int r1 = r0 + 1;
  bool has1 = (r1 < n);
  const float4* x4 = (const float4*)x;
  const float4* W1t4 = (const float4*)W1t;
  float acc0[16], acc1[16];
#pragma unroll
  for (int j = 0; j < 16; ++j) { acc0[j] = 0.f; acc1[j] = 0.f; }
  long rb0 = (long)r0 * 128 + q;
  long rb1 = (long)r1 * 128 + q;
  for (int m = 0; m < 32; ++m) {
    float4 a = x4[rb0 + m * 4];
    float4 b = has1 ? x4[rb1 + m * 4] : make_float4(0.f, 0.f, 0.f, 0.f);
    int p = q + m * 4;
#pragma unroll
    for (int j = 0; j < 16; ++j) {
      float4 w = W1t4[j * 128 + p];
      acc0[j] = fmaf(a.x, w.x, acc0[j]);
      acc0[j] = fmaf(a.y, w.y, acc0[j]);
      acc0[j] = fmaf(a.z, w.z, acc0[j]);
      acc0[j] = fmaf(a.w, w.w, acc0[j]);
      acc1[j] = fmaf(b.x, w.x, acc1[j]);
      acc1[j] = fmaf(b.y, w.y, acc1[j]);
      acc1[j] = fmaf(b.z, w.z, acc1[j]);
      acc1[j] = fmaf(b.w, w.w, acc1[j]);
    }
  }
#pragma unroll
  for (int j = 0; j < 16; ++j) {
    acc0[j] += __shfl_xor(acc0[j], 1);
    acc0[j] += __shfl_xor(acc0[j], 2);
    acc1[j] += __shfl_xor(acc1[j], 1);
    acc1[j] += __shfl_xor(acc1[j], 2);
  }
  if (q == 0) {
    float4* o4 = (float4*)h1pre;
#pragma unroll
    for (int j4 = 0; j4 < 4; ++j4) {
      o4[(long)r0 * 4 + j4] =
          make_float4(acc0[4 * j4], acc0[4 * j4 + 1], acc0[4 * j4 + 2], acc0[4 * j4 + 3]);
      if (has1)
        o4[(long)r1 * 4 + j4] =
            make_float4(acc1[4 * j4], acc1[4 * j4 + 1], acc1[4 * j4 + 2], acc1[4 * j4 + 3]);
    }
  }
}

// ---- per-bucket LDS-accumulate aggregation --------------------------------
// acc[dl][j] += w*dinv[src]*hin[src][j]; epilogue: v = dv*acc + dv^2*hin[node].
// MODE 1: out[node*16+j] = relu(v + b1[j]).
// MODE 2: out[node*64+o] = sum_j v_j * W2[j][o] + b2[o]  (fused final matmul).
template <int MODE>
__global__ __launch_bounds__(256) void k_bagg(
    const float* __restrict__ hin, const uint2* __restrict__ recs,
    const int* __restrict__ bstart, const float* __restrict__ dinv,
    const float* __restrict__ bias, const float* __restrict__ W2,
    float* __restrict__ out, int n) {
  __shared__ float acc[BKT * 16];          // 16 KB
  __shared__ float W2s[MODE == 2 ? 16 * 64 : 1];
  for (int i = threadIdx.x; i < BKT * 16; i += 256) acc[i] = 0.f;
  if (MODE == 2)
    for (int i = threadIdx.x; i < 16 * 64; i += 256) W2s[i] = W2[i];
  __syncthreads();
  int k = blockIdx.x;
  int s0 = bstart[k], s1 = bstart[k + 1];
  int j = threadIdx.x & 15;
  for (int e = s0 + (threadIdx.x >> 4); e < s1; e += 16) {
    uint2 r = recs[e];
    int src = r.x & 0xFFFFF;
    int dl = (r.x >> 20) & (BKT - 1);
    float f = __uint_as_float(r.y) * dinv[src];
    atomicAdd(&acc[dl * 16 + j], f * hin[(long)src * 16 + j]);
  }
  __syncthreads();
  int nbase = k << BKT_BITS;
  if (MODE == 1) {
    for (int i = threadIdx.x; i < BKT * 16; i += 256) {
      int node = nbase + (i >> 4), jj = i & 15;
      if (node >= n) continue;
      float dv = dinv[node];
      float v = dv * acc[i] + dv * dv * hin[(long)node * 16 + jj];
      out[(long)node * 16 + jj] = fmaxf(v + bias[jj], 0.f);
    }
  } else {
    // finish v in place, then 16x64 matmul epilogue
    for (int i = threadIdx.x; i < BKT * 16; i += 256) {
      int node = nbase + (i >> 4);
      if (node >= n) { acc[i] = 0.f; continue; }
      float dv = dinv[node];
      acc[i] = dv * acc[i] + dv * dv * hin[(long)node * 16 + (i & 15)];
    }
    __syncthreads();
    for (int f = threadIdx.x; f < BKT * 64; f += 256) {
      int nl = f >> 6, o = f & 63;
      int node = nbase + nl;
      if (node >= n) continue;
      float v = bias[o];
#pragma unroll
      for (int jj = 0; jj < 16; ++jj)
        v = fmaf(acc[nl * 16 + jj], W2s[jj * 64 + o], v);
      out[(long)node * 64 + o] = v;
    }
  }
}

extern "C" void kernel_launch(void* const* d_in, const int* in_sizes, int n_in,
                              void* d_out, int out_size, void* d_ws, size_t ws_size,
                              hipStream_t stream) {
  const float* x  = (const float*)d_in[0];
  const int*   ei = (const int*)d_in[1];
  const float* ew = (const float*)d_in[2];
  const float* W1 = (const float*)d_in[3];
  const float* b1 = (const float*)d_in[4];
  const float* W2 = (const float*)d_in[5];
  const float* b2 = (const float*)d_in[6];
  float* out = (float*)d_out;
  int n  = in_sizes[0] / 512;
  int ne = in_sizes[1] / 2;

  int nb   = (n + BKT - 1) >> BKT_BITS;      // buckets (391)
  int nblk = (ne + EPB - 1) / EPB;           // binning blocks (196)

  char* ws = (char*)d_ws;
  size_t off = 0;
  auto alloc = [&](size_t bytes) {
    size_t r = off;
    off += (bytes + 255) & ~(size_t)255;
    return r;
  };
  float* dinv   = (float*)(ws + alloc((size_t)n * 4));
  float* h1pre  = (float*)(ws + alloc((size_t)n * 16 * 4));
  float* h1     = (float*)(ws + alloc((size_t)n * 16 * 4));
  uint2* recs   = (uint2*)(ws + alloc((size_t)ne * 8));
  int*   hist   = (int*)  (ws + alloc((size_t)nblk * nb * 4));
  int*   basep  = (int*)  (ws + alloc((size_t)nblk * nb * 4));
  int*   bstart = (int*)  (ws + alloc((size_t)(nb + 1) * 4));
  (void)ws_size; (void)n_in; (void)out_size;

  size_t shb = (size_t)nb * 4;
  k_hist<<<nblk, 256, shb, stream>>>(ei + ne, hist, ne, nb);
  k_scan<<<1, 256, 0, stream>>>(hist, basep, bstart, nblk, nb);
  k_binfill<<<nblk, 256, shb, stream>>>(ei, ew, basep, recs, ne, nb);
  k_bdeg<<<nb, 256, 0, stream>>>(recs, bstart, dinv, n);

  int nrp = (n + 1) / 2;
  k_xw1<<<(nrp * 4 + 255) / 256, 256, 0, stream>>>(x, W1, h1pre, n);

  k_bagg<1><<<nb, 256, 0, stream>>>(h1pre, recs, bstart, dinv, b1, nullptr, h1, n);
  k_bagg<2><<<nb, 256, 0, stream>>>(h1, recs, bstart, dinv, b2, W2, out, n);
}

// Round 5
// 504.029 us; speedup vs baseline: 2.0378x; 2.0378x over previous
//
#include <hip/hip_runtime.h>

// GCN 2-layer: out = S·relu(S·(x·W1)+b1)·W2 + b2, S = D^-1/2 (A+I) D^-1/2
// R5: exact counting-sort (hist/scan/binfill) -> per-node CSR (k_csr: LDS
// count+scan+scatter per bucket) -> high-TLP node-major gather aggregation
// (R2-proven structure, 6250 blocks). No global scatter, no float atomics,
// no memsets. k_bagg (R4's latency-bound bucket agg) deleted.

constexpr int BKT_BITS = 8;
constexpr int BKT = 1 << BKT_BITS;   // nodes per bucket (== blockDim for k_csr)
constexpr int EPB = 16384;           // edges per binning block

// ---- pass 1: per-block bucket histogram -----------------------------------
__global__ __launch_bounds__(256) void k_hist(
    const int* __restrict__ dst, int* __restrict__ hist, int ne, int nb) {
  extern __shared__ int sh[];
  for (int i = threadIdx.x; i < nb; i += 256) sh[i] = 0;
  __syncthreads();
  int base = blockIdx.x * EPB;
  int end = min(base + EPB, ne);
  for (int e = base + threadIdx.x; e < end; e += 256)
    atomicAdd(&sh[dst[e] >> BKT_BITS], 1);
  __syncthreads();
  for (int i = threadIdx.x; i < nb; i += 256) hist[blockIdx.x * nb + i] = sh[i];
}

// ---- pass 2: exact offsets: bstart[k], base[b][k] -------------------------
__global__ void k_scan(const int* __restrict__ hist, int* __restrict__ base,
                       int* __restrict__ bstart, int nblk, int nb) {
  for (int k = threadIdx.x; k < nb; k += 256) {
    int s = 0;
    for (int b = 0; b < nblk; ++b) s += hist[b * nb + k];
    bstart[k] = s;
  }
  __syncthreads();
  if (threadIdx.x == 0) {
    int acc = 0;
    for (int k = 0; k < nb; ++k) { int v = bstart[k]; bstart[k] = acc; acc += v; }
    bstart[nb] = acc;
  }
  __syncthreads();
  for (int k = threadIdx.x; k < nb; k += 256) {
    int run = bstart[k];
    for (int b = 0; b < nblk; ++b) { base[b * nb + k] = run; run += hist[b * nb + k]; }
  }
}

// ---- pass 3: scatter records to bucket-contiguous array -------------------
// rec.x = src | (dlocal << 20), rec.y = bits(w)
__global__ __launch_bounds__(256) void k_binfill(
    const int* __restrict__ ei, const float* __restrict__ ew,
    const int* __restrict__ base, uint2* __restrict__ recs, int ne, int nb) {
  extern __shared__ int cur[];
  for (int i = threadIdx.x; i < nb; i += 256) cur[i] = base[blockIdx.x * nb + i];
  __syncthreads();
  int bs = blockIdx.x * EPB;
  int end = min(bs + EPB, ne);
  for (int e = bs + threadIdx.x; e < end; e += 256) {
    int s = ei[e];
    int d = ei[ne + e];
    float w = ew[e];
    int bkt = d >> BKT_BITS;
    int pos = atomicAdd(&cur[bkt], 1);
    recs[pos] = make_uint2((unsigned)s | ((unsigned)(d & (BKT - 1)) << 20),
                           __float_as_uint(w));
  }
}

// ---- pass 4: bucket -> per-node CSR + rowptr + dinv -----------------------
__global__ __launch_bounds__(256) void k_csr(
    const uint2* __restrict__ recs, const int* __restrict__ bstart,
    uint2* __restrict__ csr, int* __restrict__ rowptr,
    float* __restrict__ dinv, int n, int ne) {
  __shared__ float sdeg[BKT];
  __shared__ int soff[BKT];
  __shared__ int scur[BKT];
  int t = threadIdx.x;
  sdeg[t] = 0.f;
  soff[t] = 0;
  __syncthreads();
  int k = blockIdx.x;
  int s0 = bstart[k], s1 = bstart[k + 1];
  for (int e = s0 + t; e < s1; e += 256) {
    uint2 r = recs[e];
    int dl = (r.x >> 20) & (BKT - 1);
    atomicAdd(&soff[dl], 1);
    atomicAdd(&sdeg[dl], __uint_as_float(r.y));
  }
  __syncthreads();
  int v = soff[t];
  // inclusive Hillis-Steele scan over 256 counters
  for (int d = 1; d < BKT; d <<= 1) {
    int u = (t >= d) ? soff[t - d] : 0;
    __syncthreads();
    soff[t] += u;
    __syncthreads();
  }
  int excl = soff[t] - v;
  scur[t] = excl;
  int node = (k << BKT_BITS) + t;
  if (node < n) {
    rowptr[node] = s0 + excl;
    dinv[node] = 1.0f / sqrtf(sdeg[t] + 1.0f);
  }
  if (k == 0 && t == 0) rowptr[n] = ne;
  __syncthreads();
  for (int e = s0 + t; e < s1; e += 256) {
    uint2 r = recs[e];
    int dl = (r.x >> 20) & (BKT - 1);
    int pos = s0 + atomicAdd(&scur[dl], 1);
    csr[pos] = make_uint2(r.x & 0xFFFFF, r.y);
  }
}

// ---- h1pre = x @ W1  (N x 512 @ 512 x 16), unchanged from R2 --------------
__global__ __launch_bounds__(256) void k_xw1(
    const float* __restrict__ x, const float* __restrict__ W1,
    float* __restrict__ h1pre, int n) {
  __shared__ float W1t[16 * 512];
  {
#pragma unroll
    for (int i = 0; i < 32; ++i) {
      int idx = threadIdx.x + i * 256;     // source flat index = k*16 + j
      int k = idx >> 4, j = idx & 15;
      W1t[j * 512 + k] = W1[idx];
    }
  }
  __syncthreads();
  int gtid = blockIdx.x * 256 + threadIdx.x;
  int rp = gtid >> 2, q = gtid & 3;
  int r0 = rp * 2;
  if (r0 >= n) return;
  int r1 = r0 + 1;
  bool has1 = (r1 < n);
  const float4* x4 = (const float4*)x;
  const float4* W1t4 = (const float4*)W1t;
  float acc0[16], acc1[16];
#pragma unroll
  for (int j = 0; j < 16; ++j) { acc0[j] = 0.f; acc1[j] = 0.f; }
  long rb0 = (long)r0 * 128 + q;
  long rb1 = (long)r1 * 128 + q;
  for (int m = 0; m < 32; ++m) {
    float4 a = x4[rb0 + m * 4];
    float4 b = has1 ? x4[rb1 + m * 4] : make_float4(0.f, 0.f, 0.f, 0.f);
    int p = q + m * 4;
#pragma unroll
    for (int j = 0; j < 16; ++j) {
      float4 w = W1t4[j * 128 + p];
      acc0[j] = fmaf(a.x, w.x, acc0[j]);
      acc0[j] = fmaf(a.y, w.y, acc0[j]);
      acc0[j] = fmaf(a.z, w.z, acc0[j]);
      acc0[j] = fmaf(a.w, w.w, acc0[j]);
      acc1[j] = fmaf(b.x, w.x, acc1[j]);
      acc1[j] = fmaf(b.y, w.y, acc1[j]);
      acc1[j] = fmaf(b.z, w.z, acc1[j]);
      acc1[j] = fmaf(b.w, w.w, acc1[j]);
    }
  }
#pragma unroll
  for (int j = 0; j < 16; ++j) {
    acc0[j] += __shfl_xor(acc0[j], 1);
    acc0[j] += __shfl_xor(acc0[j], 2);
    acc1[j] += __shfl_xor(acc1[j], 1);
    acc1[j] += __shfl_xor(acc1[j], 2);
  }
  if (q == 0) {
    float4* o4 = (float4*)h1pre;
#pragma unroll
    for (int j4 = 0; j4 < 4; ++j4) {
      o4[(long)r0 * 4 + j4] =
          make_float4(acc0[4 * j4], acc0[4 * j4 + 1], acc0[4 * j4 + 2], acc0[4 * j4 + 3]);
      if (has1)
        o4[(long)r1 * 4 + j4] =
            make_float4(acc1[4 * j4], acc1[4 * j4 + 1], acc1[4 * j4 + 2], acc1[4 * j4 + 3]);
    }
  }
}

// ---- node-major gather-aggregate over CSR ---------------------------------
// out[i][j] = dv*(dv*hin[i][j] + sum_e w*dinv[src]*hin[src][j])
// MODE 1: +bias, relu.  MODE 2: raw.
template <int MODE>
__global__ __launch_bounds__(256) void k_agg(
    const float* __restrict__ hin, const uint2* __restrict__ csr,
    const int* __restrict__ rowptr, const float* __restrict__ dinv,
    const float* __restrict__ bias, float* __restrict__ out, int n) {
  int gtid = blockIdx.x * 256 + threadIdx.x;
  int node = gtid >> 4, j = gtid & 15;
  if (node >= n) return;
  float dv = dinv[node];
  float acc = dv * hin[(long)node * 16 + j];
  int e = rowptr[node], e1 = rowptr[node + 1];
  for (; e + 1 < e1; e += 2) {
    uint2 r0 = csr[e], r1 = csr[e + 1];
    float f0 = __uint_as_float(r0.y) * dinv[r0.x];
    float f1 = __uint_as_float(r1.y) * dinv[r1.x];
    float h0 = hin[(long)r0.x * 16 + j];
    float h1 = hin[(long)r1.x * 16 + j];
    acc = fmaf(f0, h0, acc);
    acc = fmaf(f1, h1, acc);
  }
  if (e < e1) {
    uint2 r = csr[e];
    acc = fmaf(__uint_as_float(r.y) * dinv[r.x], hin[(long)r.x * 16 + j], acc);
  }
  acc *= dv;
  if (MODE == 1)
    out[(long)node * 16 + j] = fmaxf(acc + bias[j], 0.f);
  else
    out[(long)node * 16 + j] = acc;
}

// ---- out = agg2 @ W2 + b2  (N x 16 @ 16 x 64) -----------------------------
__global__ __launch_bounds__(256) void k_out(
    const float* __restrict__ agg2, const float* __restrict__ W2,
    const float* __restrict__ b2, float* __restrict__ out, int n) {
  __shared__ float W2s[16 * 64];
#pragma unroll
  for (int s = 0; s < 4; ++s) W2s[threadIdx.x + s * 256] = W2[threadIdx.x + s * 256];
  __syncthreads();
  int gtid = blockIdx.x * 256 + threadIdx.x;
  int i = gtid >> 6, o = gtid & 63;
  if (i >= n) return;
  float acc = b2[o];
#pragma unroll
  for (int j = 0; j < 16; ++j)
    acc = fmaf(agg2[(long)i * 16 + j], W2s[j * 64 + o], acc);
  out[(long)i * 64 + o] = acc;
}

extern "C" void kernel_launch(void* const* d_in, const int* in_sizes, int n_in,
                              void* d_out, int out_size, void* d_ws, size_t ws_size,
                              hipStream_t stream) {
  const float* x  = (const float*)d_in[0];
  const int*   ei = (const int*)d_in[1];
  const float* ew = (const float*)d_in[2];
  const float* W1 = (const float*)d_in[3];
  const float* b1 = (const float*)d_in[4];
  const float* W2 = (const float*)d_in[5];
  const float* b2 = (const float*)d_in[6];
  float* out = (float*)d_out;
  int n  = in_sizes[0] / 512;
  int ne = in_sizes[1] / 2;

  int nb   = (n + BKT - 1) >> BKT_BITS;      // buckets (391)
  int nblk = (ne + EPB - 1) / EPB;           // binning blocks (196)

  char* ws = (char*)d_ws;
  size_t off = 0;
  auto alloc = [&](size_t bytes) {
    size_t r = off;
    off += (bytes + 255) & ~(size_t)255;
    return r;
  };
  float* dinv   = (float*)(ws + alloc((size_t)n * 4));
  float* h1pre  = (float*)(ws + alloc((size_t)n * 16 * 4));
  float* h1     = (float*)(ws + alloc((size_t)n * 16 * 4));
  float* agg2   = (float*)(ws + alloc((size_t)n * 16 * 4));
  uint2* recs   = (uint2*)(ws + alloc((size_t)ne * 8));
  uint2* csr    = (uint2*)(ws + alloc((size_t)ne * 8));
  int*   rowptr = (int*)  (ws + alloc((size_t)(n + 1) * 4));
  int*   hist   = (int*)  (ws + alloc((size_t)nblk * nb * 4));
  int*   basep  = (int*)  (ws + alloc((size_t)nblk * nb * 4));
  int*   bstart = (int*)  (ws + alloc((size_t)(nb + 1) * 4));
  (void)ws_size; (void)n_in; (void)out_size;

  size_t shb = (size_t)nb * 4;
  k_hist<<<nblk, 256, shb, stream>>>(ei + ne, hist, ne, nb);
  k_scan<<<1, 256, 0, stream>>>(hist, basep, bstart, nblk, nb);
  k_binfill<<<nblk, 256, shb, stream>>>(ei, ew, basep, recs, ne, nb);
  k_csr<<<nb, 256, 0, stream>>>(recs, bstart, csr, rowptr, dinv, n, ne);

  int nrp = (n + 1) / 2;
  k_xw1<<<(nrp * 4 + 255) / 256, 256, 0, stream>>>(x, W1, h1pre, n);

  int gN16 = (n * 16 + 255) / 256;
  k_agg<1><<<gN16, 256, 0, stream>>>(h1pre, csr, rowptr, dinv, b1, h1, n);
  k_agg<2><<<gN16, 256, 0, stream>>>(h1, csr, rowptr, dinv, nullptr, agg2, n);

  k_out<<<(n * 64 + 255) / 256, 256, 0, stream>>>(agg2, W2, b2, out, n);
}

// Round 6
// 340.719 us; speedup vs baseline: 3.0145x; 1.4793x over previous
//
#include <hip/hip_runtime.h>

// GCN 2-layer: out = S·relu(S·(x·W1)+b1)·W2 + b2, S = D^-1/2 (A+I) D^-1/2
// R6: R5 pipeline with the serial k_scan replaced by parallel k_colscan
// (per-bucket block scan over binning blocks) + k_scanb (single-block LDS
// scan over buckets). Offsets finalized in k_binfill (basep + bstart).

constexpr int BKT_BITS = 8;
constexpr int BKT = 1 << BKT_BITS;   // nodes per bucket (== blockDim for k_csr)
constexpr int EPB = 16384;           // edges per binning block

// ---- pass 1: per-block bucket histogram -----------------------------------
__global__ __launch_bounds__(256) void k_hist(
    const int* __restrict__ dst, int* __restrict__ hist, int ne, int nb) {
  extern __shared__ int sh[];
  for (int i = threadIdx.x; i < nb; i += 256) sh[i] = 0;
  __syncthreads();
  int base = blockIdx.x * EPB;
  int end = min(base + EPB, ne);
  for (int e = base + threadIdx.x; e < end; e += 256)
    atomicAdd(&sh[dst[e] >> BKT_BITS], 1);
  __syncthreads();
  for (int i = threadIdx.x; i < nb; i += 256) hist[blockIdx.x * nb + i] = sh[i];
}

// ---- pass 2a: per-bucket scan over binning blocks -------------------------
// basep[b][k] = exclusive prefix of hist[.][k] (partial, no bucket offset);
// colsum[k] = total edges in bucket k.
__global__ __launch_bounds__(256) void k_colscan(
    const int* __restrict__ hist, int* __restrict__ basep,
    int* __restrict__ colsum, int nblk, int nb) {
  __shared__ int sh[256];
  __shared__ int carry_s;
  int k = blockIdx.x;
  int t = threadIdx.x;
  if (t == 0) carry_s = 0;
  __syncthreads();
  for (int c0 = 0; c0 < nblk; c0 += 256) {
    int b = c0 + t;
    int v = (b < nblk) ? hist[b * nb + k] : 0;
    sh[t] = v;
    __syncthreads();
    for (int d = 1; d < 256; d <<= 1) {
      int u = (t >= d) ? sh[t - d] : 0;
      __syncthreads();
      sh[t] += u;
      __syncthreads();
    }
    if (b < nblk) basep[b * nb + k] = carry_s + sh[t] - v;
    __syncthreads();
    if (t == 0) carry_s += sh[255];
    __syncthreads();
  }
  if (t == 0) colsum[k] = carry_s;
}

// ---- pass 2b: exclusive scan over buckets (single block, LDS) -------------
__global__ __launch_bounds__(256) void k_scanb(
    const int* __restrict__ colsum, int* __restrict__ bstart, int nb) {
  __shared__ int sh[256];
  __shared__ int carry_s;
  int t = threadIdx.x;
  if (t == 0) carry_s = 0;
  __syncthreads();
  for (int c0 = 0; c0 < nb; c0 += 256) {
    int k = c0 + t;
    int v = (k < nb) ? colsum[k] : 0;
    sh[t] = v;
    __syncthreads();
    for (int d = 1; d < 256; d <<= 1) {
      int u = (t >= d) ? sh[t - d] : 0;
      __syncthreads();
      sh[t] += u;
      __syncthreads();
    }
    if (k < nb) bstart[k] = carry_s + sh[t] - v;
    __syncthreads();
    if (t == 0) carry_s += sh[255];
    __syncthreads();
  }
  if (t == 0) bstart[nb] = carry_s;
}

// ---- pass 3: scatter records to bucket-contiguous array -------------------
// rec.x = src | (dlocal << 20), rec.y = bits(w)
__global__ __launch_bounds__(256) void k_binfill(
    const int* __restrict__ ei, const float* __restrict__ ew,
    const int* __restrict__ basep, const int* __restrict__ bstart,
    uint2* __restrict__ recs, int ne, int nb) {
  extern __shared__ int cur[];
  for (int i = threadIdx.x; i < nb; i += 256)
    cur[i] = basep[blockIdx.x * nb + i] + bstart[i];
  __syncthreads();
  int bs = blockIdx.x * EPB;
  int end = min(bs + EPB, ne);
  for (int e = bs + threadIdx.x; e < end; e += 256) {
    int s = ei[e];
    int d = ei[ne + e];
    float w = ew[e];
    int bkt = d >> BKT_BITS;
    int pos = atomicAdd(&cur[bkt], 1);
    recs[pos] = make_uint2((unsigned)s | ((unsigned)(d & (BKT - 1)) << 20),
                           __float_as_uint(w));
  }
}

// ---- pass 4: bucket -> per-node CSR + rowptr + dinv -----------------------
__global__ __launch_bounds__(256) void k_csr(
    const uint2* __restrict__ recs, const int* __restrict__ bstart,
    uint2* __restrict__ csr, int* __restrict__ rowptr,
    float* __restrict__ dinv, int n, int ne) {
  __shared__ float sdeg[BKT];
  __shared__ int soff[BKT];
  __shared__ int scur[BKT];
  int t = threadIdx.x;
  sdeg[t] = 0.f;
  soff[t] = 0;
  __syncthreads();
  int k = blockIdx.x;
  int s0 = bstart[k], s1 = bstart[k + 1];
  for (int e = s0 + t; e < s1; e += 256) {
    uint2 r = recs[e];
    int dl = (r.x >> 20) & (BKT - 1);
    atomicAdd(&soff[dl], 1);
    atomicAdd(&sdeg[dl], __uint_as_float(r.y));
  }
  __syncthreads();
  int v = soff[t];
  for (int d = 1; d < BKT; d <<= 1) {
    int u = (t >= d) ? soff[t - d] : 0;
    __syncthreads();
    soff[t] += u;
    __syncthreads();
  }
  int excl = soff[t] - v;
  scur[t] = excl;
  int node = (k << BKT_BITS) + t;
  if (node < n) {
    rowptr[node] = s0 + excl;
    dinv[node] = 1.0f / sqrtf(sdeg[t] + 1.0f);
  }
  if (k == 0 && t == 0) rowptr[n] = ne;
  __syncthreads();
  for (int e = s0 + t; e < s1; e += 256) {
    uint2 r = recs[e];
    int dl = (r.x >> 20) & (BKT - 1);
    int pos = s0 + atomicAdd(&scur[dl], 1);
    csr[pos] = make_uint2(r.x & 0xFFFFF, r.y);
  }
}

// ---- h1pre = x @ W1  (N x 512 @ 512 x 16) ---------------------------------
__global__ __launch_bounds__(256) void k_xw1(
    const float* __restrict__ x, const float* __restrict__ W1,
    float* __restrict__ h1pre, int n) {
  __shared__ float W1t[16 * 512];
  {
#pragma unroll
    for (int i = 0; i < 32; ++i) {
      int idx = threadIdx.x + i * 256;     // source flat index = k*16 + j
      int k = idx >> 4, j = idx & 15;
      W1t[j * 512 + k] = W1[idx];
    }
  }
  __syncthreads();
  int gtid = blockIdx.x * 256 + threadIdx.x;
  int rp = gtid >> 2, q = gtid & 3;
  int r0 = rp * 2;
  if (r0 >= n) return;
  int r1 = r0 + 1;
  bool has1 = (r1 < n);
  const float4* x4 = (const float4*)x;
  const float4* W1t4 = (const float4*)W1t;
  float acc0[16], acc1[16];
#pragma unroll
  for (int j = 0; j < 16; ++j) { acc0[j] = 0.f; acc1[j] = 0.f; }
  long rb0 = (long)r0 * 128 + q;
  long rb1 = (long)r1 * 128 + q;
  for (int m = 0; m < 32; ++m) {
    float4 a = x4[rb0 + m * 4];
    float4 b = has1 ? x4[rb1 + m * 4] : make_float4(0.f, 0.f, 0.f, 0.f);
    int p = q + m * 4;
#pragma unroll
    for (int j = 0; j < 16; ++j) {
      float4 w = W1t4[j * 128 + p];
      acc0[j] = fmaf(a.x, w.x, acc0[j]);
      acc0[j] = fmaf(a.y, w.y, acc0[j]);
      acc0[j] = fmaf(a.z, w.z, acc0[j]);
      acc0[j] = fmaf(a.w, w.w, acc0[j]);
      acc1[j] = fmaf(b.x, w.x, acc1[j]);
      acc1[j] = fmaf(b.y, w.y, acc1[j]);
      acc1[j] = fmaf(b.z, w.z, acc1[j]);
      acc1[j] = fmaf(b.w, w.w, acc1[j]);
    }
  }
#pragma unroll
  for (int j = 0; j < 16; ++j) {
    acc0[j] += __shfl_xor(acc0[j], 1);
    acc0[j] += __shfl_xor(acc0[j], 2);
    acc1[j] += __shfl_xor(acc1[j], 1);
    acc1[j] += __shfl_xor(acc1[j], 2);
  }
  if (q == 0) {
    float4* o4 = (float4*)h1pre;
#pragma unroll
    for (int j4 = 0; j4 < 4; ++j4) {
      o4[(long)r0 * 4 + j4] =
          make_float4(acc0[4 * j4], acc0[4 * j4 + 1], acc0[4 * j4 + 2], acc0[4 * j4 + 3]);
      if (has1)
        o4[(long)r1 * 4 + j4] =
            make_float4(acc1[4 * j4], acc1[4 * j4 + 1], acc1[4 * j4 + 2], acc1[4 * j4 + 3]);
    }
  }
}

// ---- node-major gather-aggregate over CSR ---------------------------------
template <int MODE>
__global__ __launch_bounds__(256) void k_agg(
    const float* __restrict__ hin, const uint2* __restrict__ csr,
    const int* __restrict__ rowptr, const float* __restrict__ dinv,
    const float* __restrict__ bias, float* __restrict__ out, int n) {
  int gtid = blockIdx.x * 256 + threadIdx.x;
  int node = gtid >> 4, j = gtid & 15;
  if (node >= n) return;
  float dv = dinv[node];
  float acc = dv * hin[(long)node * 16 + j];
  int e = rowptr[node], e1 = rowptr[node + 1];
  for (; e + 1 < e1; e += 2) {
    uint2 r0 = csr[e], r1 = csr[e + 1];
    float f0 = __uint_as_float(r0.y) * dinv[r0.x];
    float f1 = __uint_as_float(r1.y) * dinv[r1.x];
    float h0 = hin[(long)r0.x * 16 + j];
    float h1 = hin[(long)r1.x * 16 + j];
    acc = fmaf(f0, h0, acc);
    acc = fmaf(f1, h1, acc);
  }
  if (e < e1) {
    uint2 r = csr[e];
    acc = fmaf(__uint_as_float(r.y) * dinv[r.x], hin[(long)r.x * 16 + j], acc);
  }
  acc *= dv;
  if (MODE == 1)
    out[(long)node * 16 + j] = fmaxf(acc + bias[j], 0.f);
  else
    out[(long)node * 16 + j] = acc;
}

// ---- out = agg2 @ W2 + b2  (N x 16 @ 16 x 64) -----------------------------
__global__ __launch_bounds__(256) void k_out(
    const float* __restrict__ agg2, const float* __restrict__ W2,
    const float* __restrict__ b2, float* __restrict__ out, int n) {
  __shared__ float W2s[16 * 64];
#pragma unroll
  for (int s = 0; s < 4; ++s) W2s[threadIdx.x + s * 256] = W2[threadIdx.x + s * 256];
  __syncthreads();
  int gtid = blockIdx.x * 256 + threadIdx.x;
  int i = gtid >> 6, o = gtid & 63;
  if (i >= n) return;
  float acc = b2[o];
#pragma unroll
  for (int j = 0; j < 16; ++j)
    acc = fmaf(agg2[(long)i * 16 + j], W2s[j * 64 + o], acc);
  out[(long)i * 64 + o] = acc;
}

extern "C" void kernel_launch(void* const* d_in, const int* in_sizes, int n_in,
                              void* d_out, int out_size, void* d_ws, size_t ws_size,
                              hipStream_t stream) {
  const float* x  = (const float*)d_in[0];
  const int*   ei = (const int*)d_in[1];
  const float* ew = (const float*)d_in[2];
  const float* W1 = (const float*)d_in[3];
  const float* b1 = (const float*)d_in[4];
  const float* W2 = (const float*)d_in[5];
  const float* b2 = (const float*)d_in[6];
  float* out = (float*)d_out;
  int n  = in_sizes[0] / 512;
  int ne = in_sizes[1] / 2;

  int nb   = (n + BKT - 1) >> BKT_BITS;      // buckets (391)
  int nblk = (ne + EPB - 1) / EPB;           // binning blocks (196)

  char* ws = (char*)d_ws;
  size_t off = 0;
  auto alloc = [&](size_t bytes) {
    size_t r = off;
    off += (bytes + 255) & ~(size_t)255;
    return r;
  };
  float* dinv   = (float*)(ws + alloc((size_t)n * 4));
  float* h1pre  = (float*)(ws + alloc((size_t)n * 16 * 4));
  float* h1     = (float*)(ws + alloc((size_t)n * 16 * 4));
  float* agg2   = (float*)(ws + alloc((size_t)n * 16 * 4));
  uint2* recs   = (uint2*)(ws + alloc((size_t)ne * 8));
  uint2* csr    = (uint2*)(ws + alloc((size_t)ne * 8));
  int*   rowptr = (int*)  (ws + alloc((size_t)(n + 1) * 4));
  int*   hist   = (int*)  (ws + alloc((size_t)nblk * nb * 4));
  int*   basep  = (int*)  (ws + alloc((size_t)nblk * nb * 4));
  int*   colsum = (int*)  (ws + alloc((size_t)nb * 4));
  int*   bstart = (int*)  (ws + alloc((size_t)(nb + 1) * 4));
  (void)ws_size; (void)n_in; (void)out_size;

  size_t shb = (size_t)nb * 4;
  k_hist<<<nblk, 256, shb, stream>>>(ei + ne, hist, ne, nb);
  k_colscan<<<nb, 256, 0, stream>>>(hist, basep, colsum, nblk, nb);
  k_scanb<<<1, 256, 0, stream>>>(colsum, bstart, nb);
  k_binfill<<<nblk, 256, shb, stream>>>(ei, ew, basep, bstart, recs, ne, nb);
  k_csr<<<nb, 256, 0, stream>>>(recs, bstart, csr, rowptr, dinv, n, ne);

  int nrp = (n + 1) / 2;
  k_xw1<<<(nrp * 4 + 255) / 256, 256, 0, stream>>>(x, W1, h1pre, n);

  int gN16 = (n * 16 + 255) / 256;
  k_agg<1><<<gN16, 256, 0, stream>>>(h1pre, csr, rowptr, dinv, b1, h1, n);
  k_agg<2><<<gN16, 256, 0, stream>>>(h1, csr, rowptr, dinv, nullptr, agg2, n);

  k_out<<<(n * 64 + 255) / 256, 256, 0, stream>>>(agg2, W2, b2, out, n);
}

// Round 7
// 265.650 us; speedup vs baseline: 3.8663x; 1.2826x over previous
//
#include <hip/hip_runtime.h>

// GCN 2-layer: out = S·relu(S·(x·W1)+b1)·W2 + b2, S = D^-1/2 (A+I) D^-1/2
// R7: R6 pipeline with (1) k_hist fused into the k_xw1 launch (independent
// work, union grid), (2) k_out fused into k_agg<2> via LDS W2 epilogue,
// (3) 4-deep MLP in the agg edge loop. Sort pipeline unchanged.

constexpr int BKT_BITS = 8;
constexpr int BKT = 1 << BKT_BITS;   // nodes per bucket (== blockDim for k_csr)
constexpr int EPB = 16384;           // edges per binning block

// ---- fused: x@W1 (blocks [0, xw1b)) + dst histogram (blocks [xw1b, ...)) --
__global__ __launch_bounds__(256) void k_pre(
    const float* __restrict__ x, const float* __restrict__ W1,
    float* __restrict__ h1pre, int n,
    const int* __restrict__ dst, int* __restrict__ hist, int ne, int nb,
    int xw1b) {
  __shared__ float W1t[16 * 512];          // 32 KB; hist path reuses as int[]
  if ((int)blockIdx.x >= xw1b) {
    // ---------------- histogram path ----------------
    int* sh = (int*)W1t;
    int hb = blockIdx.x - xw1b;
    for (int i = threadIdx.x; i < nb; i += 256) sh[i] = 0;
    __syncthreads();
    int base = hb * EPB;
    int end = min(base + EPB, ne);
    for (int e = base + threadIdx.x; e < end; e += 256)
      atomicAdd(&sh[dst[e] >> BKT_BITS], 1);
    __syncthreads();
    for (int i = threadIdx.x; i < nb; i += 256) hist[hb * nb + i] = sh[i];
    return;
  }
  // ---------------- x@W1 path ----------------
  {
#pragma unroll
    for (int i = 0; i < 32; ++i) {
      int idx = threadIdx.x + i * 256;     // source flat index = k*16 + j
      int k = idx >> 4, j = idx & 15;
      W1t[j * 512 + k] = W1[idx];
    }
  }
  __syncthreads();
  int gtid = blockIdx.x * 256 + threadIdx.x;
  int rp = gtid >> 2, q = gtid & 3;
  int r0 = rp * 2;
  if (r0 >= n) return;
  int r1 = r0 + 1;
  bool has1 = (r1 < n);
  const float4* x4 = (const float4*)x;
  const float4* W1t4 = (const float4*)W1t;
  float acc0[16], acc1[16];
#pragma unroll
  for (int j = 0; j < 16; ++j) { acc0[j] = 0.f; acc1[j] = 0.f; }
  long rb0 = (long)r0 * 128 + q;
  long rb1 = (long)r1 * 128 + q;
  for (int m = 0; m < 32; ++m) {
    float4 a = x4[rb0 + m * 4];
    float4 b = has1 ? x4[rb1 + m * 4] : make_float4(0.f, 0.f, 0.f, 0.f);
    int p = q + m * 4;
#pragma unroll
    for (int j = 0; j < 16; ++j) {
      float4 w = W1t4[j * 128 + p];
      acc0[j] = fmaf(a.x, w.x, acc0[j]);
      acc0[j] = fmaf(a.y, w.y, acc0[j]);
      acc0[j] = fmaf(a.z, w.z, acc0[j]);
      acc0[j] = fmaf(a.w, w.w, acc0[j]);
      acc1[j] = fmaf(b.x, w.x, acc1[j]);
      acc1[j] = fmaf(b.y, w.y, acc1[j]);
      acc1[j] = fmaf(b.z, w.z, acc1[j]);
      acc1[j] = fmaf(b.w, w.w, acc1[j]);
    }
  }
#pragma unroll
  for (int j = 0; j < 16; ++j) {
    acc0[j] += __shfl_xor(acc0[j], 1);
    acc0[j] += __shfl_xor(acc0[j], 2);
    acc1[j] += __shfl_xor(acc1[j], 1);
    acc1[j] += __shfl_xor(acc1[j], 2);
  }
  if (q == 0) {
    float4* o4 = (float4*)h1pre;
#pragma unroll
    for (int j4 = 0; j4 < 4; ++j4) {
      o4[(long)r0 * 4 + j4] =
          make_float4(acc0[4 * j4], acc0[4 * j4 + 1], acc0[4 * j4 + 2], acc0[4 * j4 + 3]);
      if (has1)
        o4[(long)r1 * 4 + j4] =
            make_float4(acc1[4 * j4], acc1[4 * j4 + 1], acc1[4 * j4 + 2], acc1[4 * j4 + 3]);
    }
  }
}

// ---- pass 2a: per-bucket scan over binning blocks -------------------------
__global__ __launch_bounds__(256) void k_colscan(
    const int* __restrict__ hist, int* __restrict__ basep,
    int* __restrict__ colsum, int nblk, int nb) {
  __shared__ int sh[256];
  __shared__ int carry_s;
  int k = blockIdx.x;
  int t = threadIdx.x;
  if (t == 0) carry_s = 0;
  __syncthreads();
  for (int c0 = 0; c0 < nblk; c0 += 256) {
    int b = c0 + t;
    int v = (b < nblk) ? hist[b * nb + k] : 0;
    sh[t] = v;
    __syncthreads();
    for (int d = 1; d < 256; d <<= 1) {
      int u = (t >= d) ? sh[t - d] : 0;
      __syncthreads();
      sh[t] += u;
      __syncthreads();
    }
    if (b < nblk) basep[b * nb + k] = carry_s + sh[t] - v;
    __syncthreads();
    if (t == 0) carry_s += sh[255];
    __syncthreads();
  }
  if (t == 0) colsum[k] = carry_s;
}

// ---- pass 2b: exclusive scan over buckets (single block, LDS) -------------
__global__ __launch_bounds__(256) void k_scanb(
    const int* __restrict__ colsum, int* __restrict__ bstart, int nb) {
  __shared__ int sh[256];
  __shared__ int carry_s;
  int t = threadIdx.x;
  if (t == 0) carry_s = 0;
  __syncthreads();
  for (int c0 = 0; c0 < nb; c0 += 256) {
    int k = c0 + t;
    int v = (k < nb) ? colsum[k] : 0;
    sh[t] = v;
    __syncthreads();
    for (int d = 1; d < 256; d <<= 1) {
      int u = (t >= d) ? sh[t - d] : 0;
      __syncthreads();
      sh[t] += u;
      __syncthreads();
    }
    if (k < nb) bstart[k] = carry_s + sh[t] - v;
    __syncthreads();
    if (t == 0) carry_s += sh[255];
    __syncthreads();
  }
  if (t == 0) bstart[nb] = carry_s;
}

// ---- pass 3: scatter records to bucket-contiguous array -------------------
__global__ __launch_bounds__(256) void k_binfill(
    const int* __restrict__ ei, const float* __restrict__ ew,
    const int* __restrict__ basep, const int* __restrict__ bstart,
    uint2* __restrict__ recs, int ne, int nb) {
  extern __shared__ int cur[];
  for (int i = threadIdx.x; i < nb; i += 256)
    cur[i] = basep[blockIdx.x * nb + i] + bstart[i];
  __syncthreads();
  int bs = blockIdx.x * EPB;
  int end = min(bs + EPB, ne);
  for (int e = bs + threadIdx.x; e < end; e += 256) {
    int s = ei[e];
    int d = ei[ne + e];
    float w = ew[e];
    int bkt = d >> BKT_BITS;
    int pos = atomicAdd(&cur[bkt], 1);
    recs[pos] = make_uint2((unsigned)s | ((unsigned)(d & (BKT - 1)) << 20),
                           __float_as_uint(w));
  }
}

// ---- pass 4: bucket -> per-node CSR + rowptr + dinv -----------------------
__global__ __launch_bounds__(256) void k_csr(
    const uint2* __restrict__ recs, const int* __restrict__ bstart,
    uint2* __restrict__ csr, int* __restrict__ rowptr,
    float* __restrict__ dinv, int n, int ne) {
  __shared__ float sdeg[BKT];
  __shared__ int soff[BKT];
  __shared__ int scur[BKT];
  int t = threadIdx.x;
  sdeg[t] = 0.f;
  soff[t] = 0;
  __syncthreads();
  int k = blockIdx.x;
  int s0 = bstart[k], s1 = bstart[k + 1];
  for (int e = s0 + t; e < s1; e += 256) {
    uint2 r = recs[e];
    int dl = (r.x >> 20) & (BKT - 1);
    atomicAdd(&soff[dl], 1);
    atomicAdd(&sdeg[dl], __uint_as_float(r.y));
  }
  __syncthreads();
  int v = soff[t];
  for (int d = 1; d < BKT; d <<= 1) {
    int u = (t >= d) ? soff[t - d] : 0;
    __syncthreads();
    soff[t] += u;
    __syncthreads();
  }
  int excl = soff[t] - v;
  scur[t] = excl;
  int node = (k << BKT_BITS) + t;
  if (node < n) {
    rowptr[node] = s0 + excl;
    dinv[node] = 1.0f / sqrtf(sdeg[t] + 1.0f);
  }
  if (k == 0 && t == 0) rowptr[n] = ne;
  __syncthreads();
  for (int e = s0 + t; e < s1; e += 256) {
    uint2 r = recs[e];
    int dl = (r.x >> 20) & (BKT - 1);
    int pos = s0 + atomicAdd(&scur[dl], 1);
    csr[pos] = make_uint2(r.x & 0xFFFFF, r.y);
  }
}

// ---- node-major gather-aggregate over CSR ---------------------------------
// MODE 1: out[node*16+j] = relu(dv*(dv*h+sum)+b1[j])      (writes h1)
// MODE 2: out[node*64+o] = sum_j v_j*W2[j][o] + b2[o]     (writes d_out)
template <int MODE>
__global__ __launch_bounds__(256) void k_agg(
    const float* __restrict__ hin, const uint2* __restrict__ csr,
    const int* __restrict__ rowptr, const float* __restrict__ dinv,
    const float* __restrict__ bias, const float* __restrict__ W2,
    float* __restrict__ out, int n) {
  __shared__ float W2s[MODE == 2 ? 16 * 64 : 1];
  __shared__ float accs[MODE == 2 ? 256 : 1];
  if (MODE == 2) {
#pragma unroll
    for (int s = 0; s < 4; ++s) W2s[threadIdx.x + s * 256] = W2[threadIdx.x + s * 256];
  }
  int gtid = blockIdx.x * 256 + threadIdx.x;
  int node = gtid >> 4, j = gtid & 15;
  bool valid = node < n;
  float acc = 0.f;
  if (valid) {
    float dv = dinv[node];
    acc = dv * hin[(long)node * 16 + j];
    int e = rowptr[node], e1 = rowptr[node + 1];
    for (; e + 3 < e1; e += 4) {
      uint2 r0 = csr[e], r1 = csr[e + 1], r2 = csr[e + 2], r3 = csr[e + 3];
      float f0 = __uint_as_float(r0.y) * dinv[r0.x];
      float f1 = __uint_as_float(r1.y) * dinv[r1.x];
      float f2 = __uint_as_float(r2.y) * dinv[r2.x];
      float f3 = __uint_as_float(r3.y) * dinv[r3.x];
      float h0 = hin[(long)r0.x * 16 + j];
      float h1 = hin[(long)r1.x * 16 + j];
      float h2 = hin[(long)r2.x * 16 + j];
      float h3 = hin[(long)r3.x * 16 + j];
      acc = fmaf(f0, h0, acc);
      acc = fmaf(f1, h1, acc);
      acc = fmaf(f2, h2, acc);
      acc = fmaf(f3, h3, acc);
    }
    for (; e < e1; ++e) {
      uint2 r = csr[e];
      acc = fmaf(__uint_as_float(r.y) * dinv[r.x], hin[(long)r.x * 16 + j], acc);
    }
    acc *= dv;
  }
  if (MODE == 1) {
    if (valid) out[(long)node * 16 + j] = fmaxf(acc + bias[j], 0.f);
    return;
  }
  // MODE 2: LDS-staged 16x64 W2 epilogue, writes final output
  accs[threadIdx.x] = acc;                       // accs[nl*16 + j]
  __syncthreads();
  int nl = threadIdx.x >> 4;
  int o4 = threadIdx.x & 15;                     // float4 column index
  int node2 = blockIdx.x * 16 + nl;
  if (node2 < n) {
    const float4* W2s4 = (const float4*)W2s;
    float4 v = ((const float4*)bias)[o4];        // bias == b2 here
#pragma unroll
    for (int jj = 0; jj < 16; ++jj) {
      float a = accs[nl * 16 + jj];
      float4 w = W2s4[jj * 16 + o4];
      v.x = fmaf(a, w.x, v.x);
      v.y = fmaf(a, w.y, v.y);
      v.z = fmaf(a, w.z, v.z);
      v.w = fmaf(a, w.w, v.w);
    }
    ((float4*)out)[(long)node2 * 16 + o4] = v;
  }
}

extern "C" void kernel_launch(void* const* d_in, const int* in_sizes, int n_in,
                              void* d_out, int out_size, void* d_ws, size_t ws_size,
                              hipStream_t stream) {
  const float* x  = (const float*)d_in[0];
  const int*   ei = (const int*)d_in[1];
  const float* ew = (const float*)d_in[2];
  const float* W1 = (const float*)d_in[3];
  const float* b1 = (const float*)d_in[4];
  const float* W2 = (const float*)d_in[5];
  const float* b2 = (const float*)d_in[6];
  float* out = (float*)d_out;
  int n  = in_sizes[0] / 512;
  int ne = in_sizes[1] / 2;

  int nb   = (n + BKT - 1) >> BKT_BITS;      // buckets (391)
  int nblk = (ne + EPB - 1) / EPB;           // binning blocks (196)

  char* ws = (char*)d_ws;
  size_t off = 0;
  auto alloc = [&](size_t bytes) {
    size_t r = off;
    off += (bytes + 255) & ~(size_t)255;
    return r;
  };
  float* dinv   = (float*)(ws + alloc((size_t)n * 4));
  float* h1pre  = (float*)(ws + alloc((size_t)n * 16 * 4));
  float* h1     = (float*)(ws + alloc((size_t)n * 16 * 4));
  uint2* recs   = (uint2*)(ws + alloc((size_t)ne * 8));
  uint2* csr    = (uint2*)(ws + alloc((size_t)ne * 8));
  int*   rowptr = (int*)  (ws + alloc((size_t)(n + 1) * 4));
  int*   hist   = (int*)  (ws + alloc((size_t)nblk * nb * 4));
  int*   basep  = (int*)  (ws + alloc((size_t)nblk * nb * 4));
  int*   colsum = (int*)  (ws + alloc((size_t)nb * 4));
  int*   bstart = (int*)  (ws + alloc((size_t)(nb + 1) * 4));
  (void)ws_size; (void)n_in; (void)out_size;

  int nrp = (n + 1) / 2;
  int xw1b = (nrp * 4 + 255) / 256;
  k_pre<<<xw1b + nblk, 256, 0, stream>>>(x, W1, h1pre, n, ei + ne, hist, ne, nb, xw1b);

  k_colscan<<<nb, 256, 0, stream>>>(hist, basep, colsum, nblk, nb);
  k_scanb<<<1, 256, 0, stream>>>(colsum, bstart, nb);
  size_t shb = (size_t)nb * 4;
  k_binfill<<<nblk, 256, shb, stream>>>(ei, ew, basep, bstart, recs, ne, nb);
  k_csr<<<nb, 256, 0, stream>>>(recs, bstart, csr, rowptr, dinv, n, ne);

  int gN16 = (n * 16 + 255) / 256;
  k_agg<1><<<gN16, 256, 0, stream>>>(h1pre, csr, rowptr, dinv, b1, nullptr, h1, n);
  k_agg<2><<<gN16, 256, 0, stream>>>(h1, csr, rowptr, dinv, b2, W2, out, n);
}

// Round 8
// 260.685 us; speedup vs baseline: 3.9400x; 1.0190x over previous
//
#include <hip/hip_runtime.h>

// GCN 2-layer: out = S·relu(S·(x·W1)+b1)·W2 + b2, S = D^-1/2 (A+I) D^-1/2
// R8: dinv folded into feature tables (h1pre scaled in k_csr tail; agg1
// epilogue emits dinv*relu(...)), agg re-laned to 4 lanes/node with float4
// loads (per-edge inst count halved, no per-edge dinv gather). Sort pipeline
// unchanged from R7.

constexpr int BKT_BITS = 8;
constexpr int BKT = 1 << BKT_BITS;   // nodes per bucket (== blockDim for k_csr)
constexpr int EPB = 16384;           // edges per binning block

// ---- fused: x@W1 (blocks [0, xw1b)) + dst histogram (blocks [xw1b, ...)) --
__global__ __launch_bounds__(256) void k_pre(
    const float* __restrict__ x, const float* __restrict__ W1,
    float* __restrict__ h1pre, int n,
    const int* __restrict__ dst, int* __restrict__ hist, int ne, int nb,
    int xw1b) {
  __shared__ float W1t[16 * 512];          // 32 KB; hist path reuses as int[]
  if ((int)blockIdx.x >= xw1b) {
    int* sh = (int*)W1t;
    int hb = blockIdx.x - xw1b;
    for (int i = threadIdx.x; i < nb; i += 256) sh[i] = 0;
    __syncthreads();
    int base = hb * EPB;
    int end = min(base + EPB, ne);
    for (int e = base + threadIdx.x; e < end; e += 256)
      atomicAdd(&sh[dst[e] >> BKT_BITS], 1);
    __syncthreads();
    for (int i = threadIdx.x; i < nb; i += 256) hist[hb * nb + i] = sh[i];
    return;
  }
  {
#pragma unroll
    for (int i = 0; i < 32; ++i) {
      int idx = threadIdx.x + i * 256;     // source flat index = k*16 + j
      int k = idx >> 4, j = idx & 15;
      W1t[j * 512 + k] = W1[idx];
    }
  }
  __syncthreads();
  int gtid = blockIdx.x * 256 + threadIdx.x;
  int rp = gtid >> 2, q = gtid & 3;
  int r0 = rp * 2;
  if (r0 >= n) return;
  int r1 = r0 + 1;
  bool has1 = (r1 < n);
  const float4* x4 = (const float4*)x;
  const float4* W1t4 = (const float4*)W1t;
  float acc0[16], acc1[16];
#pragma unroll
  for (int j = 0; j < 16; ++j) { acc0[j] = 0.f; acc1[j] = 0.f; }
  long rb0 = (long)r0 * 128 + q;
  long rb1 = (long)r1 * 128 + q;
  for (int m = 0; m < 32; ++m) {
    float4 a = x4[rb0 + m * 4];
    float4 b = has1 ? x4[rb1 + m * 4] : make_float4(0.f, 0.f, 0.f, 0.f);
    int p = q + m * 4;
#pragma unroll
    for (int j = 0; j < 16; ++j) {
      float4 w = W1t4[j * 128 + p];
      acc0[j] = fmaf(a.x, w.x, acc0[j]);
      acc0[j] = fmaf(a.y, w.y, acc0[j]);
      acc0[j] = fmaf(a.z, w.z, acc0[j]);
      acc0[j] = fmaf(a.w, w.w, acc0[j]);
      acc1[j] = fmaf(b.x, w.x, acc1[j]);
      acc1[j] = fmaf(b.y, w.y, acc1[j]);
      acc1[j] = fmaf(b.z, w.z, acc1[j]);
      acc1[j] = fmaf(b.w, w.w, acc1[j]);
    }
  }
#pragma unroll
  for (int j = 0; j < 16; ++j) {
    acc0[j] += __shfl_xor(acc0[j], 1);
    acc0[j] += __shfl_xor(acc0[j], 2);
    acc1[j] += __shfl_xor(acc1[j], 1);
    acc1[j] += __shfl_xor(acc1[j], 2);
  }
  if (q == 0) {
    float4* o4 = (float4*)h1pre;
#pragma unroll
    for (int j4 = 0; j4 < 4; ++j4) {
      o4[(long)r0 * 4 + j4] =
          make_float4(acc0[4 * j4], acc0[4 * j4 + 1], acc0[4 * j4 + 2], acc0[4 * j4 + 3]);
      if (has1)
        o4[(long)r1 * 4 + j4] =
            make_float4(acc1[4 * j4], acc1[4 * j4 + 1], acc1[4 * j4 + 2], acc1[4 * j4 + 3]);
    }
  }
}

// ---- pass 2a: per-bucket scan over binning blocks -------------------------
__global__ __launch_bounds__(256) void k_colscan(
    const int* __restrict__ hist, int* __restrict__ basep,
    int* __restrict__ colsum, int nblk, int nb) {
  __shared__ int sh[256];
  __shared__ int carry_s;
  int k = blockIdx.x;
  int t = threadIdx.x;
  if (t == 0) carry_s = 0;
  __syncthreads();
  for (int c0 = 0; c0 < nblk; c0 += 256) {
    int b = c0 + t;
    int v = (b < nblk) ? hist[b * nb + k] : 0;
    sh[t] = v;
    __syncthreads();
    for (int d = 1; d < 256; d <<= 1) {
      int u = (t >= d) ? sh[t - d] : 0;
      __syncthreads();
      sh[t] += u;
      __syncthreads();
    }
    if (b < nblk) basep[b * nb + k] = carry_s + sh[t] - v;
    __syncthreads();
    if (t == 0) carry_s += sh[255];
    __syncthreads();
  }
  if (t == 0) colsum[k] = carry_s;
}

// ---- pass 2b: exclusive scan over buckets (single block, LDS) -------------
__global__ __launch_bounds__(256) void k_scanb(
    const int* __restrict__ colsum, int* __restrict__ bstart, int nb) {
  __shared__ int sh[256];
  __shared__ int carry_s;
  int t = threadIdx.x;
  if (t == 0) carry_s = 0;
  __syncthreads();
  for (int c0 = 0; c0 < nb; c0 += 256) {
    int k = c0 + t;
    int v = (k < nb) ? colsum[k] : 0;
    sh[t] = v;
    __syncthreads();
    for (int d = 1; d < 256; d <<= 1) {
      int u = (t >= d) ? sh[t - d] : 0;
      __syncthreads();
      sh[t] += u;
      __syncthreads();
    }
    if (k < nb) bstart[k] = carry_s + sh[t] - v;
    __syncthreads();
    if (t == 0) carry_s += sh[255];
    __syncthreads();
  }
  if (t == 0) bstart[nb] = carry_s;
}

// ---- pass 3: scatter records to bucket-contiguous array -------------------
__global__ __launch_bounds__(256) void k_binfill(
    const int* __restrict__ ei, const float* __restrict__ ew,
    const int* __restrict__ basep, const int* __restrict__ bstart,
    uint2* __restrict__ recs, int ne, int nb) {
  extern __shared__ int cur[];
  for (int i = threadIdx.x; i < nb; i += 256)
    cur[i] = basep[blockIdx.x * nb + i] + bstart[i];
  __syncthreads();
  int bs = blockIdx.x * EPB;
  int end = min(bs + EPB, ne);
  for (int e = bs + threadIdx.x; e < end; e += 256) {
    int s = ei[e];
    int d = ei[ne + e];
    float w = ew[e];
    int bkt = d >> BKT_BITS;
    int pos = atomicAdd(&cur[bkt], 1);
    recs[pos] = make_uint2((unsigned)s | ((unsigned)(d & (BKT - 1)) << 20),
                           __float_as_uint(w));
  }
}

// ---- pass 4: bucket -> per-node CSR + rowptr + dinv + h1pre scaling -------
__global__ __launch_bounds__(256) void k_csr(
    const uint2* __restrict__ recs, const int* __restrict__ bstart,
    uint2* __restrict__ csr, int* __restrict__ rowptr,
    float* __restrict__ dinv, float* __restrict__ h1pre, int n, int ne) {
  __shared__ float sdeg[BKT];
  __shared__ int soff[BKT];
  __shared__ int scur[BKT];
  int t = threadIdx.x;
  sdeg[t] = 0.f;
  soff[t] = 0;
  __syncthreads();
  int k = blockIdx.x;
  int s0 = bstart[k], s1 = bstart[k + 1];
  for (int e = s0 + t; e < s1; e += 256) {
    uint2 r = recs[e];
    int dl = (r.x >> 20) & (BKT - 1);
    atomicAdd(&soff[dl], 1);
    atomicAdd(&sdeg[dl], __uint_as_float(r.y));
  }
  __syncthreads();
  int v = soff[t];
  for (int d = 1; d < BKT; d <<= 1) {
    int u = (t >= d) ? soff[t - d] : 0;
    __syncthreads();
    soff[t] += u;
    __syncthreads();
  }
  int excl = soff[t] - v;
  scur[t] = excl;
  int node = (k << BKT_BITS) + t;
  float dvv = 0.f;
  if (node < n) {
    dvv = 1.0f / sqrtf(sdeg[t] + 1.0f);
    rowptr[node] = s0 + excl;
    dinv[node] = dvv;
  }
  sdeg[t] = dvv;                 // reuse: per-node dinv for the scale loop
  if (k == 0 && t == 0) rowptr[n] = ne;
  __syncthreads();
  for (int e = s0 + t; e < s1; e += 256) {
    uint2 r = recs[e];
    int dl = (r.x >> 20) & (BKT - 1);
    int pos = s0 + atomicAdd(&scur[dl], 1);
    csr[pos] = make_uint2(r.x & 0xFFFFF, r.y);
  }
  // fused: h1pre[node][*] *= dinv[node] for this bucket's nodes (coalesced)
  int nbase = k << BKT_BITS;
  int lim4 = (min(n - nbase, BKT)) * 4;    // float4 count in bucket
  float4* h4 = (float4*)h1pre + (long)nbase * 4;
  for (int i = t; i < lim4; i += 256) {
    float dv2 = sdeg[i >> 2];
    float4 hv = h4[i];
    hv.x *= dv2; hv.y *= dv2; hv.z *= dv2; hv.w *= dv2;
    h4[i] = hv;
  }
}

// ---- node-major gather-aggregate over CSR (4 lanes/node, float4) ----------
// hin is pre-scaled by dinv (h'). acc = h'[node] + sum_e w*h'[src]; v = dv*acc.
// MODE 1: out[node] = dv*relu(v + b1)   (emits h1' = dinv*relu(...))
// MODE 2: out[node*64+o] = sum_j v_j*W2[j][o] + b2[o]   (writes d_out)
template <int MODE>
__global__ __launch_bounds__(256) void k_agg(
    const float* __restrict__ hin, const uint2* __restrict__ csr,
    const int* __restrict__ rowptr, const float* __restrict__ dinv,
    const float* __restrict__ bias, const float* __restrict__ W2,
    float* __restrict__ out, int n) {
  __shared__ float W2s[MODE == 2 ? 16 * 64 : 1];
  __shared__ float accs[MODE == 2 ? 64 * 16 : 1];
  if (MODE == 2) {
#pragma unroll
    for (int s = 0; s < 4; ++s) W2s[threadIdx.x + s * 256] = W2[threadIdx.x + s * 256];
  }
  const float4* hin4 = (const float4*)hin;
  int gtid = blockIdx.x * 256 + threadIdx.x;
  int node = gtid >> 2, q = gtid & 3;
  bool valid = node < n;
  float4 acc = make_float4(0.f, 0.f, 0.f, 0.f);
  float dv = 0.f;
  if (valid) {
    dv = dinv[node];
    acc = hin4[(long)node * 4 + q];            // self term h'[node]
    int e = rowptr[node], e1 = rowptr[node + 1];
    for (; e + 3 < e1; e += 4) {
      uint2 r0 = csr[e], r1 = csr[e + 1], r2 = csr[e + 2], r3 = csr[e + 3];
      float4 h0 = hin4[(long)r0.x * 4 + q];
      float4 h1 = hin4[(long)r1.x * 4 + q];
      float4 h2 = hin4[(long)r2.x * 4 + q];
      float4 h3 = hin4[(long)r3.x * 4 + q];
      float f0 = __uint_as_float(r0.y), f1 = __uint_as_float(r1.y);
      float f2 = __uint_as_float(r2.y), f3 = __uint_as_float(r3.y);
      acc.x = fmaf(f0, h0.x, acc.x); acc.y = fmaf(f0, h0.y, acc.y);
      acc.z = fmaf(f0, h0.z, acc.z); acc.w = fmaf(f0, h0.w, acc.w);
      acc.x = fmaf(f1, h1.x, acc.x); acc.y = fmaf(f1, h1.y, acc.y);
      acc.z = fmaf(f1, h1.z, acc.z); acc.w = fmaf(f1, h1.w, acc.w);
      acc.x = fmaf(f2, h2.x, acc.x); acc.y = fmaf(f2, h2.y, acc.y);
      acc.z = fmaf(f2, h2.z, acc.z); acc.w = fmaf(f2, h2.w, acc.w);
      acc.x = fmaf(f3, h3.x, acc.x); acc.y = fmaf(f3, h3.y, acc.y);
      acc.z = fmaf(f3, h3.z, acc.z); acc.w = fmaf(f3, h3.w, acc.w);
    }
    for (; e < e1; ++e) {
      uint2 r = csr[e];
      float4 h = hin4[(long)r.x * 4 + q];
      float f = __uint_as_float(r.y);
      acc.x = fmaf(f, h.x, acc.x); acc.y = fmaf(f, h.y, acc.y);
      acc.z = fmaf(f, h.z, acc.z); acc.w = fmaf(f, h.w, acc.w);
    }
    acc.x *= dv; acc.y *= dv; acc.z *= dv; acc.w *= dv;   // v = dv*acc
  }
  if (MODE == 1) {
    if (valid) {
      float4 b = ((const float4*)bias)[q];
      float4 o;
      o.x = dv * fmaxf(acc.x + b.x, 0.f);
      o.y = dv * fmaxf(acc.y + b.y, 0.f);
      o.z = dv * fmaxf(acc.z + b.z, 0.f);
      o.w = dv * fmaxf(acc.w + b.w, 0.f);
      ((float4*)out)[(long)node * 4 + q] = o;
    }
    return;
  }
  // MODE 2: LDS-staged 16x64 W2 epilogue (64 nodes per block)
  ((float4*)accs)[threadIdx.x] = acc;          // accs[(tid>>2)*16 + (tid&3)*4 ..]
  __syncthreads();
  const float4* W2s4 = (const float4*)W2s;
#pragma unroll
  for (int it = 0; it < 4; ++it) {
    int nl = it * 16 + (threadIdx.x >> 4);
    int o4 = threadIdx.x & 15;
    int node2 = blockIdx.x * 64 + nl;
    if (node2 < n) {
      float4 v = ((const float4*)bias)[o4];
#pragma unroll
      for (int jj = 0; jj < 16; ++jj) {
        float a = accs[nl * 16 + jj];
        float4 w = W2s4[jj * 16 + o4];
        v.x = fmaf(a, w.x, v.x);
        v.y = fmaf(a, w.y, v.y);
        v.z = fmaf(a, w.z, v.z);
        v.w = fmaf(a, w.w, v.w);
      }
      ((float4*)out)[(long)node2 * 16 + o4] = v;
    }
  }
}

extern "C" void kernel_launch(void* const* d_in, const int* in_sizes, int n_in,
                              void* d_out, int out_size, void* d_ws, size_t ws_size,
                              hipStream_t stream) {
  const float* x  = (const float*)d_in[0];
  const int*   ei = (const int*)d_in[1];
  const float* ew = (const float*)d_in[2];
  const float* W1 = (const float*)d_in[3];
  const float* b1 = (const float*)d_in[4];
  const float* W2 = (const float*)d_in[5];
  const float* b2 = (const float*)d_in[6];
  float* out = (float*)d_out;
  int n  = in_sizes[0] / 512;
  int ne = in_sizes[1] / 2;

  int nb   = (n + BKT - 1) >> BKT_BITS;      // buckets (391)
  int nblk = (ne + EPB - 1) / EPB;           // binning blocks (196)

  char* ws = (char*)d_ws;
  size_t off = 0;
  auto alloc = [&](size_t bytes) {
    size_t r = off;
    off += (bytes + 255) & ~(size_t)255;
    return r;
  };
  float* dinv   = (float*)(ws + alloc((size_t)n * 4));
  float* h1pre  = (float*)(ws + alloc((size_t)n * 16 * 4));
  float* h1     = (float*)(ws + alloc((size_t)n * 16 * 4));
  uint2* recs   = (uint2*)(ws + alloc((size_t)ne * 8));
  uint2* csr    = (uint2*)(ws + alloc((size_t)ne * 8));
  int*   rowptr = (int*)  (ws + alloc((size_t)(n + 1) * 4));
  int*   hist   = (int*)  (ws + alloc((size_t)nblk * nb * 4));
  int*   basep  = (int*)  (ws + alloc((size_t)nblk * nb * 4));
  int*   colsum = (int*)  (ws + alloc((size_t)nb * 4));
  int*   bstart = (int*)  (ws + alloc((size_t)(nb + 1) * 4));
  (void)ws_size; (void)n_in; (void)out_size;

  int nrp = (n + 1) / 2;
  int xw1b = (nrp * 4 + 255) / 256;
  k_pre<<<xw1b + nblk, 256, 0, stream>>>(x, W1, h1pre, n, ei + ne, hist, ne, nb, xw1b);

  k_colscan<<<nb, 256, 0, stream>>>(hist, basep, colsum, nblk, nb);
  k_scanb<<<1, 256, 0, stream>>>(colsum, bstart, nb);
  size_t shb = (size_t)nb * 4;
  k_binfill<<<nblk, 256, shb, stream>>>(ei, ew, basep, bstart, recs, ne, nb);
  k_csr<<<nb, 256, 0, stream>>>(recs, bstart, csr, rowptr, dinv, h1pre, n, ne);

  int gN4 = (n * 4 + 255) / 256;
  k_agg<1><<<gN4, 256, 0, stream>>>(h1pre, csr, rowptr, dinv, b1, nullptr, h1, n);
  k_agg<2><<<gN4, 256, 0, stream>>>(h1, csr, rowptr, dinv, b2, W2, out, n);
}